// Round 11
// baseline (1148.985 us; speedup 1.0000x reference)
//
#include <hip/hip_runtime.h>
#include <hip/hip_bf16.h>

#define NA 35
#define NM 18
#define NN 53
#define TT 48
#define HH 32
#define OUT_MEO_BASE (1024*35*32)
#define XHS 72     // stride in u16 for xh and pbf rows (144 B: 16B-aligned, 2-way LDS conflicts only)

typedef unsigned short u16;
typedef __attribute__((ext_vector_type(8))) short s8v;   // 8 bf16 (4 VGPRs) MFMA A/B frag
typedef __attribute__((ext_vector_type(4))) float f4v;   // MFMA C/D frag

__device__ __forceinline__ float bfu(u16 u){ return __uint_as_float(((unsigned)u)<<16); }
__device__ __forceinline__ u16 cvtbf(float f){
  unsigned u = __float_as_uint(f);
  return (u16)((u + 0x7FFFu + ((u>>16)&1u)) >> 16);   // round-to-nearest-even
}

struct Params {
  const void *X_aqi, *X_meo, *ctx, *adj, *adjn;
  const void *emb0,*emb1,*emb2,*emb3,*emb4,*emb5,*emb6,*emb7,*emb8;
  const void *Wxa,*Wxm,*Wua,*Wum;
  const void *a0,*a1,*a2,*a3;
  const void *wih_a,*whh_a,*bih_a,*bhh_a,*wih_m,*whh_m,*bih_m,*bhh_m;
  const int *Xae,*Xme;
  void* out;
};

__device__ __forceinline__ float ldf(const void* p, int i, bool isbf){
  return isbf ? bfu(((const u16*)p)[i]) : ((const float*)p)[i];
}
__device__ __forceinline__ u16 ldraw(const void* p, int i, bool isbf){
  return isbf ? ((const u16*)p)[i] : cvtbf(((const float*)p)[i]);
}

// LDS dieted to 75264 B (granule-rounded) == r4's PROVEN 2-blocks/CU point.
// aAll (3008 B) removed: the a-vectors are setup-only (stage 2) and are now
// read straight from global (L2-hot, one-time). Steady-state loop identical
// to r10. All three GEMMs (attri, softmax@attri, GRU) on MFMA.
struct __align__(16) Smem {
  alignas(16) float gb[4][96];       // bih_a, bhh_a, bih_m, bhh_m (fp32)
  alignas(16) float embA[304];
  alignas(16) float ctxS[NN][2], ctxD[NN][2];
  alignas(16) float uSrc[2][2][14];
  alignas(16) float uDst[2][2][14];
  alignas(16) u16   biasE[NN*56];    // bf16: adj_norm*a[184] or -1e12
  alignas(16) float xin[NN*16];      // fp32 features+embeddings (logits use 14)
  alignas(16) u16   xinbf[64*32];    // bf16 A operand for attri MFMA:
                                     // aqi rows: raw x in cols 0..5; meo rows: cols 8..11; rest 0
  alignas(16) u16   wfA[2*64*8];     // attri B-frags (nt=0,1): rows 0..5=Wxa, 8..11=Wxm, else 0
  alignas(16) u16   afrag[4*64*8];   // attri as ph4 B-frags: ((kt*2+nt)*64+lane)*8+j
                                     //  = attri[k=kt*32+(lane>>4)*8+j][n=nt*16+(lane&15)]; k>=53 zero
  alignas(16) float srcv[NN*2], dstv[NN*2];
  alignas(16) u16   pbf[64*XHS];     // P (exp(e-mx), unnormalized) bf16 row-major; pads zero
  alignas(16) float inv[56];
  alignas(16) u16   xh[64*XHS];      // MFMA A operand: [0:32)=gx, [32:64)=h (bf16)
  alignas(16) float h[NN*32];        // fp32 hidden state (carry precision)
  alignas(16) u16   wfrag[2*12*64*8]; // GRU B-frags, fragment-ordered (r2-verified)
};

// 512 threads, plain bounds (r4-r7: explicit min-waves bounds spill).
// Natural allocation 96 arch VGPR; with LDS at 75264 (r4's proven point)
// the HW should place 2 blocks/CU (16 waves, 4/SIMD).
__global__ __launch_bounds__(512)
void chgat_gru_kernel(Params p){
  __shared__ Smem sm;
  const int tid = threadIdx.x;
  const int b = blockIdx.x;

  // ---------- stage 0: dtype detection (adj is exactly {0,1}) ----------
  bool isbf = false;
  {
    const unsigned* aw = (const unsigned*)p.adj;
    for (int i=0;i<32;++i){
      unsigned w = aw[i];
      if (w != 0u && w != 0x3F800000u) isbf = true;
    }
  }
  // a-vector selector (branchy select, no private array -> no scratch)
  auto aPtr = [&](int s)->const void*{
    return s==0 ? p.a0 : s==1 ? p.a1 : s==2 ? p.a2 : p.a3;
  };

  // ---------- stage 1: stage constants into LDS ----------
  if (tid < 96){
    sm.gb[0][tid]=ldf(p.bih_a,tid,isbf); sm.gb[1][tid]=ldf(p.bhh_a,tid,isbf);
    sm.gb[2][tid]=ldf(p.bih_m,tid,isbf); sm.gb[3][tid]=ldf(p.bhh_m,tid,isbf);
  }
  if (tid < 70)  sm.embA[tid]        = ldf(p.emb0, tid, isbf);
  if (tid < 26)  sm.embA[70+tid]     = ldf(p.emb1, tid, isbf);
  if (tid < 14)  sm.embA[96+tid]     = ldf(p.emb2, tid, isbf);
  if (tid < 48)  sm.embA[110+tid]    = ldf(p.emb3, tid, isbf);
  if (tid < 18)  sm.embA[158+tid]    = ldf(p.emb4, tid, isbf);
  if (tid < 36)  sm.embA[176+tid]    = ldf(p.emb5, tid, isbf);
  if (tid < 26)  sm.embA[212+tid]    = ldf(p.emb6, tid, isbf);
  if (tid < 14)  sm.embA[238+tid]    = ldf(p.emb7, tid, isbf);
  if (tid < 48)  sm.embA[252+tid]    = ldf(p.emb8, tid, isbf);
  for (int idx=tid; idx<NN*32; idx+=512) sm.h[idx] = 0.f;
  for (int idx=tid; idx<64*XHS; idx+=512) sm.xh[idx] = 0;   // h=0 at t=0; pads stay 0
  for (int idx=tid; idx<64*XHS; idx+=512) sm.pbf[idx] = 0;  // row/col pads stay 0 forever
  for (int idx=tid; idx<4*64*8; idx+=512) sm.afrag[idx] = 0; // K-pad nodes 53-63 stay 0
  for (int idx=tid; idx<64*32; idx+=512) sm.xinbf[idx] = 0; // unused cols/rows stay 0
  // attri B-frags: one 16x16x32 B per nt; K-rows 0..5 = Wxa, 8..11 = Wxm, else 0
  if (tid < 128){
    int l = tid & 63, nl2 = l & 15, qd2 = l >> 4, nt = tid >> 6;
    u16* dst = &sm.wfA[tid*8];
    #pragma unroll
    for (int j=0;j<8;++j){
      int k = qd2*8 + j, n = nt*16 + nl2;
      u16 v = 0;
      if (k < 6)              v = ldraw(p.Wxa, k*32+n, isbf);
      else if (k>=8 && k<12)  v = ldraw(p.Wxm, (k-8)*32+n, isbf);
      dst[j] = v;
    }
  }
  // GRU weights -> LDS, fragment-ordered (once; 3 lane-frags per thread)
  for (int u = tid; u < 2*12*64; u += 512){
    int wty2 = u / (12*64);
    int rem  = u - wty2*(12*64);
    int f = rem >> 6, l = rem & 63;
    int nl2 = l & 15, qd2 = l >> 4;
    const void* W = (f < 6) ? (wty2 ? p.wih_m : p.wih_a) : (wty2 ? p.whh_m : p.whh_a);
    int fr = (f < 6) ? f : f - 6;
    int base = (fr*16 + nl2)*32 + qd2*8;
    u16* dst = &sm.wfrag[u*8];
    #pragma unroll
    for (int j=0;j<8;++j) dst[j] = ldraw(W, base+j, isbf);
  }
  __syncthreads();

  // ---------- stage 2: batch-invariant attention constants (a-vecs from global) ----------
  if (tid < 212){
    int i = tid>>2, v = tid&3, it = (i<NA)?0:1;
    int sel = (v<2) ? (it*2+v) : ((v-2)*2+it);
    int off = (v<2) ? 32 : 124;
    const void* ap = aPtr(sel);
    float s = 0.f;
    for (int c=0;c<60;++c) s += ldf(p.ctx, i*60+c, isbf)*ldf(ap, off+c, isbf);
    if (v < 2) sm.ctxS[i][v] = s; else sm.ctxD[i][v-2] = s;
  }
  if (tid < 112){
    int u = tid;
    int it = u / 56, rem = u % 56;
    int sd = rem / 28, rem2 = rem % 28;
    int v = rem2 / 14, k = rem2 % 14;
    const void* Wu = it ? p.Wum : p.Wua;
    int sel = sd ? (v*2+it) : (it*2+v);
    int off = sd ? 92 : 0;
    const void* ap = aPtr(sel);
    float s = 0.f;
    for (int kk=0;kk<32;++kk) s += ldf(Wu, k*32+kk, isbf)*ldf(ap, off+kk, isbf);
    if (sd) sm.uDst[it][v][k] = s; else sm.uSrc[it][v][k] = s;
  }
  for (int idx=tid; idx<NN*NN; idx+=512){
    int i = idx/NN, j = idx - i*NN;
    int sel = ((i<NA)?0:2) + ((j<NA)?0:1);
    float ad = ldf(p.adj, idx, isbf);
    sm.biasE[i*56+j] = cvtbf((ad > 0.f) ? ldf(p.adjn, idx, isbf)*ldf(aPtr(sel),184,isbf) : -1e12f);
  }
  __syncthreads();

  const int ng   = tid >> 6;        // wave 0..7
  const int lane = tid & 63;
  const int nl   = lane & 15;       // MFMA col/row-in-tile index
  const int qd   = lane >> 4;       // MFMA quad

  // ph5 wave->pass map: waves 0-2 aqi tiles 0,1,2; wave 3 tile2-meo; wave 4 tile3-meo.
  const int wty = (ng==3 || ng==4) ? 1 : 0;
  const s8v* wfB = ((const s8v*)sm.wfrag) + (wty*12*64 + lane);

  // ---------- prefetch t=0 (512 slots over 512 threads, one each) ----------
  float rvf = 0.f; int rvi = 0;
  {
    int bt = b*TT + 0;
    if      (tid < 210) rvf = ldf(p.X_aqi, bt*210 + tid, isbf);
    else if (tid < 282) rvf = ldf(p.X_meo, bt*72 + tid - 210, isbf);
    else if (tid < 422) rvi = p.Xae[bt*140 + tid - 282];
    else                rvi = p.Xme[bt*90  + tid - 422];
  }

  #pragma unroll 1
  for (int t=0; t<TT; ++t){
    // ---- ph0: scatter prefetched inputs into xin (+bf16 copy of raw x) ----
    if (tid < 210){
      int n = tid/6, e = tid%6;
      sm.xin[n*16 + e] = rvf;
      sm.xinbf[n*32 + e] = cvtbf(rvf);          // aqi K-rows 0..5
    } else if (tid < 282){
      int q = tid-210; int n = NA + (q>>2), e = q&3;
      sm.xin[n*16 + e] = rvf;
      sm.xinbf[n*32 + 8 + e] = cvtbf(rvf);      // meo K-rows 8..11
    } else if (tid < 422){
      int u = tid - 282;
      int n = u>>2, e = u&3;
      int off = (e==0)?0:(e==1)?70:(e==2)?96:110;
      sm.xin[n*16 + 6 + 2*e]     = sm.embA[off + rvi*2];
      sm.xin[n*16 + 6 + 2*e + 1] = sm.embA[off + rvi*2 + 1];
    } else {
      int q = tid - 422;
      int n = NA + q/5, e = q%5;
      int off = (e==0)?158:(e==1)?176:(e==2)?212:(e==3)?238:252;
      sm.xin[n*16 + 4 + 2*e]     = sm.embA[off + rvi*2];
      sm.xin[n*16 + 4 + 2*e + 1] = sm.embA[off + rvi*2 + 1];
    }
    // prefetch t+1
    {
      int tn = (t < TT-1) ? t+1 : t;
      int bt = b*TT + tn;
      if      (tid < 210) rvf = ldf(p.X_aqi, bt*210 + tid, isbf);
      else if (tid < 282) rvf = ldf(p.X_meo, bt*72 + tid - 210, isbf);
      else if (tid < 422) rvi = p.Xae[bt*140 + tid - 282];
      else                rvi = p.Xme[bt*90  + tid - 422];
    }
    __syncthreads();   // (A) xin/xinbf ready; prior-step h writes visible

    // ---- ph1: attri via MFMA (8 waves = 8 (mt,nt) tiles) + src/dst logits ----
    {
      const int mt = ng >> 1, nt = ng & 1;
      s8v A0 = *(const s8v*)&sm.xinbf[(mt*16 + nl)*32 + qd*8];
      s8v B0 = ((const s8v*)sm.wfA)[nt*64 + lane];
      f4v acc = {0,0,0,0};
      acc = __builtin_amdgcn_mfma_f32_16x16x32_bf16(A0, B0, acc, 0,0,0);
      #pragma unroll
      for (int r=0;r<4;++r){
        int row = mt*16 + qd*4 + r;   // node; C/D: col=lane&15, row=(lane>>4)*4+reg
        if (row < NN){
          int fi = ((row>>5)*2 + nt)*64 + (nl + (((row>>3)&3)<<4));
          sm.afrag[fi*8 + (row&7)] = cvtbf(acc[r]);
        }
      }
    }
    if (tid < 212){
      int i = tid>>2, v = tid&3, it2 = (i<NA)?0:1;
      const float* x = &sm.xin[i*16];
      float sacc; const float* uv;
      if (v < 2){ sacc = sm.ctxS[i][v];   uv = sm.uSrc[it2][v]; }
      else      { sacc = sm.ctxD[i][v-2]; uv = sm.uDst[it2][v-2]; }
      #pragma unroll
      for (int k=0;k<14;++k) sacc += x[k]*uv[k];
      if (v < 2) sm.srcv[i*2+v] = sacc; else sm.dstv[i*2+(v-2)] = sacc;
    }
    __syncthreads();   // (B) afrag, srcv, dstv ready

    // ---- ph3: masked softmax rows (8 lanes/row); e recomputed pass-2 (no p[]) ----
    if (tid < 424){
      int i = tid>>3, l = tid&7, it2 = (i<NA)?0:1;
      float s0 = sm.srcv[i*2+0], s1 = sm.srcv[i*2+1];
      float mx = -3.0e38f;
      for (int j=l; j<NN; j+=8){
        float e = ((j<NA)? s0 : s1) + sm.dstv[j*2+it2] + bfu(sm.biasE[i*56+j]);
        e = (e >= 0.f) ? e : 0.2f*e;
        mx = fmaxf(mx, e);
      }
      mx = fmaxf(mx, __shfl_xor(mx,1,64));
      mx = fmaxf(mx, __shfl_xor(mx,2,64));
      mx = fmaxf(mx, __shfl_xor(mx,4,64));
      float sum = 0.f;
      for (int j=l; j<NN; j+=8){
        float e = ((j<NA)? s0 : s1) + sm.dstv[j*2+it2] + bfu(sm.biasE[i*56+j]);
        e = (e >= 0.f) ? e : 0.2f*e;
        float pe = __expf(e - mx);
        sm.pbf[i*XHS+j] = cvtbf(pe);     // unnormalized P, bf16 (A operand)
        sum += pe;
      }
      sum += __shfl_xor(sum,1,64);
      sum += __shfl_xor(sum,2,64);
      sum += __shfl_xor(sum,4,64);
      if (l == 0) sm.inv[i] = 1.0f/sum;
    }
    __syncthreads();   // (C) pbf, inv ready

    // ---- ph4: gx = (P @ attri) * inv  via MFMA; 8 waves = 8 (mt,nt) tiles ----
    {
      const int mt = ng >> 1;          // M-tile 0..3 (rows mt*16..mt*16+15)
      const int nt = ng & 1;           // N-tile 0..1 (dims nt*16..nt*16+15)
      const u16* arow = &sm.pbf[(mt*16 + nl)*XHS + qd*8];
      s8v A0 = *(const s8v*)arow;            // k 0..31
      s8v A1 = *(const s8v*)(arow + 32);     // k 32..63 (cols 53-63 zero)
      const s8v* bf = (const s8v*)sm.afrag;
      s8v B0 = bf[(0*2+nt)*64 + lane];
      s8v B1 = bf[(1*2+nt)*64 + lane];
      f4v acc = {0,0,0,0};
      acc = __builtin_amdgcn_mfma_f32_16x16x32_bf16(A0, B0, acc, 0,0,0);
      acc = __builtin_amdgcn_mfma_f32_16x16x32_bf16(A1, B1, acc, 0,0,0);
      const int dcol = nt*16 + nl;
      #pragma unroll
      for (int r=0;r<4;++r){
        int row = mt*16 + qd*4 + r;    // C/D layout: col=lane&15, row=(lane>>4)*4+reg
        if (row < NN) sm.xh[row*XHS + dcol] = cvtbf(acc[r] * sm.inv[row]);
      }
    }
    __syncthreads();   // (D) xh x-part ready for all waves' A-fragments

    // ---- ph5: GRU via MFMA, B-frags streamed from LDS (conflict-free).
    // One pass per wave (waves 0-4), two sequential half-passes (4 accums
    // live) to keep total regs <= 128 so a second block can co-reside.
    {
      const bool last = (t == TT-1);
      auto run_pass = [&](int mt, int tp){
        const u16* xr = &sm.xh[(mt*16 + nl)*XHS + qd*8];
        s8v A0 = *(const s8v*)xr;          // k 0..31 (x)
        s8v A1 = *(const s8v*)(xr + 32);   // k 32..63 (h)
        const float* bi = tp ? sm.gb[2] : sm.gb[0];
        const float* bh = tp ? sm.gb[3] : sm.gb[1];
        #pragma unroll 1
        for (int hf=0; hf<2; ++hf){
          f4v aR={0,0,0,0}, aZ={0,0,0,0}, aI={0,0,0,0}, aG={0,0,0,0};
          aR = __builtin_amdgcn_mfma_f32_16x16x32_bf16(A0, wfB[(0+hf)*64],  aR, 0,0,0);
          aR = __builtin_amdgcn_mfma_f32_16x16x32_bf16(A1, wfB[(6+hf)*64],  aR, 0,0,0);
          aZ = __builtin_amdgcn_mfma_f32_16x16x32_bf16(A0, wfB[(2+hf)*64],  aZ, 0,0,0);
          aZ = __builtin_amdgcn_mfma_f32_16x16x32_bf16(A1, wfB[(8+hf)*64],  aZ, 0,0,0);
          aI = __builtin_amdgcn_mfma_f32_16x16x32_bf16(A0, wfB[(4+hf)*64],  aI, 0,0,0);
          aG = __builtin_amdgcn_mfma_f32_16x16x32_bf16(A1, wfB[(10+hf)*64], aG, 0,0,0);
          const int dd = nl + hf*16;
          float br=bi[dd]+bh[dd], bz=bi[32+dd]+bh[32+dd], bn=bi[64+dd], bg=bh[64+dd];
          #pragma unroll
          for (int r=0;r<4;++r){
            int node = mt*16 + qd*4 + r;      // C/D layout: row=(lane>>4)*4+reg
            bool valid = tp ? (node>=NA && node<NN) : (node<NA);
            if (valid){
              float hold = sm.h[node*32+dd];
              float rr = 1.f/(1.f+__expf(-(aR[r]+br)));
              float zz = 1.f/(1.f+__expf(-(aZ[r]+bz)));
              float pr = (aI[r]+bn) + rr*(aG[r]+bg);
              float e2 = __expf(2.f*pr);
              float hn = (1.f-zz)*(1.f-2.f/(e2+1.f)) + zz*hold;
              sm.h[node*32+dd] = hn;
              sm.xh[node*XHS+32+dd] = cvtbf(hn);
              if (last){
                long long oi = tp ? ((long long)OUT_MEO_BASE + (long long)b*(NM*HH) + (long long)(node-NA)*32)
                                  : ((long long)b*(NA*HH) + (long long)node*32);
                if (isbf) ((u16*)p.out)[oi+dd]=cvtbf(hn);
                else      ((float*)p.out)[oi+dd]=hn;
              }
            }
          }
        }
      };
      if      (ng==0) run_pass(0,0);
      else if (ng==1) run_pass(1,0);
      else if (ng==2) run_pass(2,0);   // mixed tile, aqi rows 32-34
      else if (ng==3) run_pass(2,1);   // mixed tile, meo rows 35-47
      else if (ng==4) run_pass(3,1);   // tile3, meo rows 48-52
      // waves 5-7 idle in ph5
    }
    // loop tail: epilogue h writes ordered vs next step's readers by barrier (A)
  }
}

extern "C" void kernel_launch(void* const* d_in, const int* in_sizes, int n_in,
                              void* d_out, int out_size, void* d_ws, size_t ws_size,
                              hipStream_t stream){
  (void)in_sizes; (void)n_in; (void)d_ws; (void)ws_size; (void)out_size;
  Params p;
  p.X_aqi = d_in[0];
  p.X_meo = d_in[1];
  p.ctx   = d_in[2];
  p.adj   = d_in[3];
  p.adjn  = d_in[4];
  p.emb0 = d_in[5];  p.emb1 = d_in[6];
  p.emb2 = d_in[7];  p.emb3 = d_in[8];
  p.emb4 = d_in[9];  p.emb5 = d_in[10];
  p.emb6 = d_in[11]; p.emb7 = d_in[12];
  p.emb8 = d_in[13];
  p.Wxa = d_in[14]; p.Wxm = d_in[15];
  p.Wua = d_in[16]; p.Wum = d_in[17];
  p.a0 = d_in[18]; p.a1 = d_in[19];
  p.a2 = d_in[20]; p.a3 = d_in[21];
  p.wih_a = d_in[22]; p.whh_a = d_in[23];
  p.bih_a = d_in[24]; p.bhh_a = d_in[25];
  p.wih_m = d_in[26]; p.whh_m = d_in[27];
  p.bih_m = d_in[28]; p.bhh_m = d_in[29];
  p.Xae = (const int*)d_in[30];
  p.Xme = (const int*)d_in[31];
  p.out = d_out;
  hipLaunchKernelGGL(chgat_gru_kernel, dim3(1024), dim3(512), 0, stream, p);
}

// Round 12
// 994.384 us; speedup vs baseline: 1.1555x; 1.1555x over previous
//
#include <hip/hip_runtime.h>
#include <hip/hip_bf16.h>

#define NA 35
#define NM 18
#define NN 53
#define TT 48
#define HH 32
#define OUT_MEO_BASE (1024*35*32)
#define XHS 72     // stride in u16 for xh and pbf rows (144 B: 16B-aligned, 2-way LDS conflicts only)

typedef unsigned short u16;
typedef __attribute__((ext_vector_type(8))) short s8v;   // 8 bf16 (4 VGPRs) MFMA A/B frag
typedef __attribute__((ext_vector_type(4))) float f4v;   // MFMA C/D frag

__device__ __forceinline__ float bfu(u16 u){ return __uint_as_float(((unsigned)u)<<16); }
__device__ __forceinline__ u16 cvtbf(float f){
  unsigned u = __float_as_uint(f);
  return (u16)((u + 0x7FFFu + ((u>>16)&1u)) >> 16);   // round-to-nearest-even
}

struct Params {
  const void *X_aqi, *X_meo, *ctx, *adj, *adjn;
  const void *emb0,*emb1,*emb2,*emb3,*emb4,*emb5,*emb6,*emb7,*emb8;
  const void *Wxa,*Wxm,*Wua,*Wum;
  const void *a0,*a1,*a2,*a3;
  const void *wih_a,*whh_a,*bih_a,*bhh_a,*wih_m,*whh_m,*bih_m,*bhh_m;
  const int *Xae,*Xme;
  void* out;
};

__device__ __forceinline__ float ldf(const void* p, int i, bool isbf){
  return isbf ? bfu(((const u16*)p)[i]) : ((const float*)p)[i];
}
__device__ __forceinline__ u16 ldraw(const void* p, int i, bool isbf){
  return isbf ? ((const u16*)p)[i] : cvtbf(((const float*)p)[i]);
}

// Per-batch mutable state: threads 0-255 drive bs[0] (batch 2b), threads
// 256-511 drive bs[1] (batch 2b+1).
struct __align__(16) BatchState {
  alignas(16) float xin[NN*16];      // fp32 features+embeddings (logits use 14)
  alignas(16) u16   xinbf[64*32];    // bf16 A for attri MFMA: aqi rows cols 0..5, meo rows cols 8..11, rest 0
  alignas(16) u16   afrag[4*64*8];   // attri as ph4 B-frags: ((kt*2+nt)*64+lane)*8+j ; k>=53 zero
  alignas(16) float srcv[NN*2], dstv[NN*2];
  alignas(16) u16   pbf[64*XHS];     // P (exp(e-mx), unnormalized) bf16 row-major; pads zero
  alignas(16) float inv[56];
  alignas(16) u16   xh[64*XHS];      // MFMA A: [0:32)=gx, [32:64)=h (bf16)
  alignas(16) float h[NN*32];        // fp32 hidden state (carry precision)
};

// ~112.4 KB LDS: 36.6 KB invariant + 2 x 37.9 KB batch state. One block/CU
// (co-residency of two 512-thread blocks proved unreachable r10/r11); the
// second independent batch lives INSIDE the block instead -> grid halves to
// 512 -> 2 serial rounds per CU instead of 4, and the two halves' dependency
// chains interleave at every barrier.
struct __align__(16) Smem {
  alignas(16) float gb[4][96];       // bih_a, bhh_a, bih_m, bhh_m (fp32)
  alignas(16) float embA[304];
  alignas(16) float ctxS[NN][2], ctxD[NN][2];
  alignas(16) float uSrc[2][2][14];
  alignas(16) float uDst[2][2][14];
  alignas(16) u16   biasE[NN*56];    // bf16: adj_norm*a[184] or -1e12
  alignas(16) u16   wfA[2*64*8];     // attri B-frags (nt=0,1): K-rows 0..5=Wxa, 8..11=Wxm, else 0
  alignas(16) u16   wfrag[2*12*64*8]; // GRU B-frags, fragment-ordered (r2-verified)
  BatchState bs[2];
};

// 512 threads, plain bounds -> 128-arch cap (measured r3/r5-r7). The r5
// dual-batch attempt needed ~190 regs (fat pre-MFMA body) and spilled; the
// MFMA-ized body measures 96 at 512 threads (r11), and dual-batch live state
// is the same (loops double, state doesn't) -> fits 128 spill-free now.
__global__ __launch_bounds__(512)
void chgat_gru_kernel(Params p){
  __shared__ Smem sm;
  const int tid = threadIdx.x;
  const int bid = blockIdx.x;

  // ---------- stage 0: dtype detection (adj is exactly {0,1}) ----------
  bool isbf = false;
  {
    const unsigned* aw = (const unsigned*)p.adj;
    for (int i=0;i<32;++i){
      unsigned w = aw[i];
      if (w != 0u && w != 0x3F800000u) isbf = true;
    }
  }
  // a-vector selector (branchy select, no private array -> no scratch)
  auto aPtr = [&](int s)->const void*{
    return s==0 ? p.a0 : s==1 ? p.a1 : s==2 ? p.a2 : p.a3;
  };

  // ---------- stage 1: stage constants into LDS (batch-invariant) ----------
  if (tid < 96){
    sm.gb[0][tid]=ldf(p.bih_a,tid,isbf); sm.gb[1][tid]=ldf(p.bhh_a,tid,isbf);
    sm.gb[2][tid]=ldf(p.bih_m,tid,isbf); sm.gb[3][tid]=ldf(p.bhh_m,tid,isbf);
  }
  if (tid < 70)  sm.embA[tid]        = ldf(p.emb0, tid, isbf);
  if (tid < 26)  sm.embA[70+tid]     = ldf(p.emb1, tid, isbf);
  if (tid < 14)  sm.embA[96+tid]     = ldf(p.emb2, tid, isbf);
  if (tid < 48)  sm.embA[110+tid]    = ldf(p.emb3, tid, isbf);
  if (tid < 18)  sm.embA[158+tid]    = ldf(p.emb4, tid, isbf);
  if (tid < 36)  sm.embA[176+tid]    = ldf(p.emb5, tid, isbf);
  if (tid < 26)  sm.embA[212+tid]    = ldf(p.emb6, tid, isbf);
  if (tid < 14)  sm.embA[238+tid]    = ldf(p.emb7, tid, isbf);
  if (tid < 48)  sm.embA[252+tid]    = ldf(p.emb8, tid, isbf);
  for (int idx=tid; idx<2*NN*32; idx+=512) sm.bs[idx/(NN*32)].h[idx%(NN*32)] = 0.f;
  for (int idx=tid; idx<2*64*XHS; idx+=512) sm.bs[idx/(64*XHS)].xh[idx%(64*XHS)] = 0;
  for (int idx=tid; idx<2*64*XHS; idx+=512) sm.bs[idx/(64*XHS)].pbf[idx%(64*XHS)] = 0;
  for (int idx=tid; idx<2*4*64*8; idx+=512) sm.bs[idx/(4*64*8)].afrag[idx%(4*64*8)] = 0;
  for (int idx=tid; idx<2*64*32; idx+=512) sm.bs[idx/(64*32)].xinbf[idx%(64*32)] = 0;
  // attri B-frags: one 16x16x32 B per nt; K-rows 0..5 = Wxa, 8..11 = Wxm, else 0
  if (tid < 128){
    int l = tid & 63, nl2 = l & 15, qd2 = l >> 4, nt = tid >> 6;
    u16* dst = &sm.wfA[tid*8];
    #pragma unroll
    for (int j=0;j<8;++j){
      int k = qd2*8 + j, n = nt*16 + nl2;
      u16 v = 0;
      if (k < 6)              v = ldraw(p.Wxa, k*32+n, isbf);
      else if (k>=8 && k<12)  v = ldraw(p.Wxm, (k-8)*32+n, isbf);
      dst[j] = v;
    }
  }
  // GRU weights -> LDS, fragment-ordered (once; 3 lane-frags per thread)
  for (int u = tid; u < 2*12*64; u += 512){
    int wty2 = u / (12*64);
    int rem  = u - wty2*(12*64);
    int f = rem >> 6, l = rem & 63;
    int nl2 = l & 15, qd2 = l >> 4;
    const void* W = (f < 6) ? (wty2 ? p.wih_m : p.wih_a) : (wty2 ? p.whh_m : p.whh_a);
    int fr = (f < 6) ? f : f - 6;
    int base = (fr*16 + nl2)*32 + qd2*8;
    u16* dst = &sm.wfrag[u*8];
    #pragma unroll
    for (int j=0;j<8;++j) dst[j] = ldraw(W, base+j, isbf);
  }
  __syncthreads();

  // ---------- stage 2: batch-invariant attention constants (a-vecs from global) ----------
  if (tid < 212){
    int i = tid>>2, v = tid&3, it = (i<NA)?0:1;
    int sel = (v<2) ? (it*2+v) : ((v-2)*2+it);
    int off = (v<2) ? 32 : 124;
    const void* ap = aPtr(sel);
    float s = 0.f;
    for (int c=0;c<60;++c) s += ldf(p.ctx, i*60+c, isbf)*ldf(ap, off+c, isbf);
    if (v < 2) sm.ctxS[i][v] = s; else sm.ctxD[i][v-2] = s;
  }
  if (tid < 112){
    int u = tid;
    int it = u / 56, rem = u % 56;
    int sd = rem / 28, rem2 = rem % 28;
    int v = rem2 / 14, k = rem2 % 14;
    const void* Wu = it ? p.Wum : p.Wua;
    int sel = sd ? (v*2+it) : (it*2+v);
    int off = sd ? 92 : 0;
    const void* ap = aPtr(sel);
    float s = 0.f;
    for (int kk=0;kk<32;++kk) s += ldf(Wu, k*32+kk, isbf)*ldf(ap, off+kk, isbf);
    if (sd) sm.uDst[it][v][k] = s; else sm.uSrc[it][v][k] = s;
  }
  for (int idx=tid; idx<NN*NN; idx+=512){
    int i = idx/NN, j = idx - i*NN;
    int sel = ((i<NA)?0:2) + ((j<NA)?0:1);
    float ad = ldf(p.adj, idx, isbf);
    sm.biasE[i*56+j] = cvtbf((ad > 0.f) ? ldf(p.adjn, idx, isbf)*ldf(aPtr(sel),184,isbf) : -1e12f);
  }
  __syncthreads();

  // ---------- half-block decomposition ----------
  const int hb   = tid >> 8;        // 0 or 1 (batch within block)
  const int lt   = tid & 255;       // local tid within half
  const int lw   = lt >> 6;         // local wave 0..3
  const int lane = tid & 63;        // hardware lane (waves never straddle halves)
  const int nl   = lane & 15;       // MFMA col/row-in-tile index
  const int qd   = lane >> 4;       // MFMA quad
  const int bb   = 2*bid + hb;      // this half's batch element

  BatchState& st = sm.bs[hb];
  // ph5 wave->pass map (per half, r0-verified): lw 0-2 aqi tiles, lw 3 both meo passes.
  const int wty = (lw==3) ? 1 : 0;
  const s8v* wfB = ((const s8v*)sm.wfrag) + (wty*12*64 + lane);

  // ---------- prefetch t=0 (512 slots over 256 threads per half) ----------
  float rv1 = 0.f, rv2r = 0.f; int rv2i = 0;
  {
    int bt = bb*TT + 0;
    rv1 = (lt < 210) ? ldf(p.X_aqi, bt*210 + lt, isbf) : ldf(p.X_meo, bt*72 + lt - 210, isbf);
    if (lt < 26) rv2r = ldf(p.X_meo, bt*72 + lt + 46, isbf);
    else { int u = lt - 26; rv2i = (u < 140) ? p.Xae[bt*140 + u] : p.Xme[bt*90 + u - 140]; }
  }

  #pragma unroll 1
  for (int t=0; t<TT; ++t){
    // ---- ph0: scatter prefetched inputs into xin (+bf16 raw x into xinbf) ----
    if (lt < 210){
      int n = lt/6, e = lt%6;
      st.xin[n*16 + e] = rv1;
      st.xinbf[n*32 + e] = cvtbf(rv1);            // aqi K-rows 0..5
    } else {
      int q = lt-210; int n = NA + (q>>2), e = q&3;  // meo raw 0..45
      st.xin[n*16 + e] = rv1;
      st.xinbf[n*32 + 8 + e] = cvtbf(rv1);        // meo K-rows 8..11
    }
    if (lt < 26){
      int q = lt + 46; int n = NA + (q>>2), e = q&3; // meo raw 46..71
      st.xin[n*16 + e] = rv2r;
      st.xinbf[n*32 + 8 + e] = cvtbf(rv2r);
    } else {
      int u = lt - 26;
      if (u < 140){
        int n = u>>2, e = u&3;
        int off = (e==0)?0:(e==1)?70:(e==2)?96:110;
        st.xin[n*16 + 6 + 2*e]     = sm.embA[off + rv2i*2];
        st.xin[n*16 + 6 + 2*e + 1] = sm.embA[off + rv2i*2 + 1];
      } else {
        int q = u - 140;
        int n = NA + q/5, e = q%5;
        int off = (e==0)?158:(e==1)?176:(e==2)?212:(e==3)?238:252;
        st.xin[n*16 + 4 + 2*e]     = sm.embA[off + rv2i*2];
        st.xin[n*16 + 4 + 2*e + 1] = sm.embA[off + rv2i*2 + 1];
      }
    }
    // prefetch t+1
    {
      int tn = (t < TT-1) ? t+1 : t;
      int bt = bb*TT + tn;
      rv1 = (lt < 210) ? ldf(p.X_aqi, bt*210 + lt, isbf) : ldf(p.X_meo, bt*72 + lt - 210, isbf);
      if (lt < 26) rv2r = ldf(p.X_meo, bt*72 + lt + 46, isbf);
      else { int u = lt - 26; rv2i = (u < 140) ? p.Xae[bt*140 + u] : p.Xme[bt*90 + u - 140]; }
    }
    __syncthreads();   // (A) xin/xinbf ready; prior-step h writes visible

    // ---- ph1: attri via MFMA (4 waves/half; wave lw -> M-tile lw, both nt) + logits ----
    {
      s8v A0 = *(const s8v*)&st.xinbf[(lw*16 + nl)*32 + qd*8];
      #pragma unroll 1
      for (int nt=0; nt<2; ++nt){
        s8v B0 = ((const s8v*)sm.wfA)[nt*64 + lane];
        f4v acc = {0,0,0,0};
        acc = __builtin_amdgcn_mfma_f32_16x16x32_bf16(A0, B0, acc, 0,0,0);
        #pragma unroll
        for (int r=0;r<4;++r){
          int row = lw*16 + qd*4 + r;   // node; C/D: col=lane&15, row=(lane>>4)*4+reg
          if (row < NN){
            int fi = ((row>>5)*2 + nt)*64 + (nl + (((row>>3)&3)<<4));
            st.afrag[fi*8 + (row&7)] = cvtbf(acc[r]);
          }
        }
      }
    }
    if (lt < 212){
      int i = lt>>2, v = lt&3, it2 = (i<NA)?0:1;
      const float* x = &st.xin[i*16];
      float sacc; const float* uv;
      if (v < 2){ sacc = sm.ctxS[i][v];   uv = sm.uSrc[it2][v]; }
      else      { sacc = sm.ctxD[i][v-2]; uv = sm.uDst[it2][v-2]; }
      #pragma unroll
      for (int k=0;k<14;++k) sacc += x[k]*uv[k];
      if (v < 2) st.srcv[i*2+v] = sacc; else st.dstv[i*2+(v-2)] = sacc;
    }
    __syncthreads();   // (B) afrag, srcv, dstv ready

    // ---- ph3: masked softmax rows (4 lanes/row per half); e recomputed pass-2 ----
    if (lt < 212){
      int i = lt>>2, l = lt&3, it2 = (i<NA)?0:1;
      float s0 = st.srcv[i*2+0], s1 = st.srcv[i*2+1];
      float mx = -3.0e38f;
      for (int j=l; j<NN; j+=4){
        float e = ((j<NA)? s0 : s1) + st.dstv[j*2+it2] + bfu(sm.biasE[i*56+j]);
        e = (e >= 0.f) ? e : 0.2f*e;
        mx = fmaxf(mx, e);
      }
      mx = fmaxf(mx, __shfl_xor(mx,1,64));
      mx = fmaxf(mx, __shfl_xor(mx,2,64));
      float sum = 0.f;
      for (int j=l; j<NN; j+=4){
        float e = ((j<NA)? s0 : s1) + st.dstv[j*2+it2] + bfu(sm.biasE[i*56+j]);
        e = (e >= 0.f) ? e : 0.2f*e;
        float pe = __expf(e - mx);
        st.pbf[i*XHS+j] = cvtbf(pe);     // unnormalized P, bf16 (A operand)
        sum += pe;
      }
      sum += __shfl_xor(sum,1,64);
      sum += __shfl_xor(sum,2,64);
      if (l == 0) st.inv[i] = 1.0f/sum;
    }
    __syncthreads();   // (C) pbf, inv ready

    // ---- ph4: gx = (P @ attri) * inv via MFMA; wave lw -> M-tile lw, both nt ----
    {
      const u16* arow = &st.pbf[(lw*16 + nl)*XHS + qd*8];
      s8v A0 = *(const s8v*)arow;            // k 0..31
      s8v A1 = *(const s8v*)(arow + 32);     // k 32..63 (cols 53-63 zero)
      const s8v* bf = (const s8v*)st.afrag;
      #pragma unroll 1
      for (int nt=0; nt<2; ++nt){
        s8v B0 = bf[(0*2+nt)*64 + lane];
        s8v B1 = bf[(1*2+nt)*64 + lane];
        f4v acc = {0,0,0,0};
        acc = __builtin_amdgcn_mfma_f32_16x16x32_bf16(A0, B0, acc, 0,0,0);
        acc = __builtin_amdgcn_mfma_f32_16x16x32_bf16(A1, B1, acc, 0,0,0);
        const int dcol = nt*16 + nl;
        #pragma unroll
        for (int r=0;r<4;++r){
          int row = lw*16 + qd*4 + r;    // C/D: col=lane&15, row=(lane>>4)*4+reg
          if (row < NN) st.xh[row*XHS + dcol] = cvtbf(acc[r] * st.inv[row]);
        }
      }
    }
    __syncthreads();   // (D) xh x-part ready for all waves' A-fragments

    // ---- ph5: GRU via MFMA; per half lw 0-2 one aqi pass, lw 3 both meo passes.
    // hf half-pass split keeps live pressure to {A0,A1, 4 accums, 6 frags}.
    {
      const bool last = (t == TT-1);
      auto run_pass = [&](int mt, int tp){
        const u16* xr = &st.xh[(mt*16 + nl)*XHS + qd*8];
        s8v A0 = *(const s8v*)xr;          // k 0..31 (x)
        s8v A1 = *(const s8v*)(xr + 32);   // k 32..63 (h)
        const float* bi = tp ? sm.gb[2] : sm.gb[0];
        const float* bh = tp ? sm.gb[3] : sm.gb[1];
        #pragma unroll 1
        for (int hf=0; hf<2; ++hf){
          f4v aR={0,0,0,0}, aZ={0,0,0,0}, aI={0,0,0,0}, aG={0,0,0,0};
          aR = __builtin_amdgcn_mfma_f32_16x16x32_bf16(A0, wfB[(0+hf)*64],  aR, 0,0,0);
          aR = __builtin_amdgcn_mfma_f32_16x16x32_bf16(A1, wfB[(6+hf)*64],  aR, 0,0,0);
          aZ = __builtin_amdgcn_mfma_f32_16x16x32_bf16(A0, wfB[(2+hf)*64],  aZ, 0,0,0);
          aZ = __builtin_amdgcn_mfma_f32_16x16x32_bf16(A1, wfB[(8+hf)*64],  aZ, 0,0,0);
          aI = __builtin_amdgcn_mfma_f32_16x16x32_bf16(A0, wfB[(4+hf)*64],  aI, 0,0,0);
          aG = __builtin_amdgcn_mfma_f32_16x16x32_bf16(A1, wfB[(10+hf)*64], aG, 0,0,0);
          const int dd = nl + hf*16;
          float br=bi[dd]+bh[dd], bz=bi[32+dd]+bh[32+dd], bn=bi[64+dd], bg=bh[64+dd];
          #pragma unroll
          for (int r=0;r<4;++r){
            int node = mt*16 + qd*4 + r;      // C/D layout: row=(lane>>4)*4+reg
            bool valid = tp ? (node>=NA && node<NN) : (node<NA);
            if (valid){
              float hold = st.h[node*32+dd];
              float rr = 1.f/(1.f+__expf(-(aR[r]+br)));
              float zz = 1.f/(1.f+__expf(-(aZ[r]+bz)));
              float pr = (aI[r]+bn) + rr*(aG[r]+bg);
              float e2 = __expf(2.f*pr);
              float hn = (1.f-zz)*(1.f-2.f/(e2+1.f)) + zz*hold;
              st.h[node*32+dd] = hn;
              st.xh[node*XHS+32+dd] = cvtbf(hn);
              if (last){
                long long oi = tp ? ((long long)OUT_MEO_BASE + (long long)bb*(NM*HH) + (long long)(node-NA)*32)
                                  : ((long long)bb*(NA*HH) + (long long)node*32);
                if (isbf) ((u16*)p.out)[oi+dd]=cvtbf(hn);
                else      ((float*)p.out)[oi+dd]=hn;
              }
            }
          }
        }
      };
      if (lw < 3) run_pass(lw, 0);             // aqi tiles 0,1,2 (rows 0-34)
      else { run_pass(2,1); run_pass(3,1); }   // meo rows 35-47; rows 48-52
    }
    // loop tail: epilogue h writes ordered vs next step's readers by barrier (A)
  }
}

extern "C" void kernel_launch(void* const* d_in, const int* in_sizes, int n_in,
                              void* d_out, int out_size, void* d_ws, size_t ws_size,
                              hipStream_t stream){
  (void)in_sizes; (void)n_in; (void)d_ws; (void)ws_size; (void)out_size;
  Params p;
  p.X_aqi = d_in[0];
  p.X_meo = d_in[1];
  p.ctx   = d_in[2];
  p.adj   = d_in[3];
  p.adjn  = d_in[4];
  p.emb0 = d_in[5];  p.emb1 = d_in[6];
  p.emb2 = d_in[7];  p.emb3 = d_in[8];
  p.emb4 = d_in[9];  p.emb5 = d_in[10];
  p.emb6 = d_in[11]; p.emb7 = d_in[12];
  p.emb8 = d_in[13];
  p.Wxa = d_in[14]; p.Wxm = d_in[15];
  p.Wua = d_in[16]; p.Wum = d_in[17];
  p.a0 = d_in[18]; p.a1 = d_in[19];
  p.a2 = d_in[20]; p.a3 = d_in[21];
  p.wih_a = d_in[22]; p.whh_a = d_in[23];
  p.bih_a = d_in[24]; p.bhh_a = d_in[25];
  p.wih_m = d_in[26]; p.whh_m = d_in[27];
  p.bih_m = d_in[28]; p.bhh_m = d_in[29];
  p.Xae = (const int*)d_in[30];
  p.Xme = (const int*)d_in[31];
  p.out = d_out;
  hipLaunchKernelGGL(chgat_gru_kernel, dim3(512), dim3(512), 0, stream, p);
}

// Round 13
// 862.860 us; speedup vs baseline: 1.3316x; 1.1524x over previous
//
#include <hip/hip_runtime.h>
#include <hip/hip_bf16.h>

#define NA 35
#define NM 18
#define NN 53
#define TT 48
#define HH 32
#define OUT_MEO_BASE (1024*35*32)
#define XHS 72     // stride in u16 for xh and pbf rows (144 B: 16B-aligned, 2-way LDS conflicts only)

typedef unsigned short u16;
typedef __attribute__((ext_vector_type(8))) short s8v;   // 8 bf16 (4 VGPRs) MFMA A/B frag
typedef __attribute__((ext_vector_type(4))) float f4v;   // MFMA C/D frag

__device__ __forceinline__ float bfu(u16 u){ return __uint_as_float(((unsigned)u)<<16); }
__device__ __forceinline__ u16 cvtbf(float f){
  unsigned u = __float_as_uint(f);
  return (u16)((u + 0x7FFFu + ((u>>16)&1u)) >> 16);   // round-to-nearest-even
}

struct Params {
  const void *X_aqi, *X_meo, *ctx, *adj, *adjn;
  const void *emb0,*emb1,*emb2,*emb3,*emb4,*emb5,*emb6,*emb7,*emb8;
  const void *Wxa,*Wxm,*Wua,*Wum;
  const void *a0,*a1,*a2,*a3;
  const void *wih_a,*whh_a,*bih_a,*bhh_a,*wih_m,*whh_m,*bih_m,*bhh_m;
  const int *Xae,*Xme;
  void* out;
};

__device__ __forceinline__ float ldf(const void* p, int i, bool isbf){
  return isbf ? bfu(((const u16*)p)[i]) : ((const float*)p)[i];
}
__device__ __forceinline__ u16 ldraw(const void* p, int i, bool isbf){
  return isbf ? ((const u16*)p)[i] : cvtbf(((const float*)p)[i]);
}

// Per-batch state, 30.4 KB. LIFETIME UNION: uni[] is pbf (P bf16, live
// ph3->ph4) AND {xin fp32 @byte 0 (3392 B) + xinbf @byte 3392 (4096 B)}
// (live ph0->ph1). Alias map in u16 indices: xin=[0,1696), xinbf=[1696,3744),
// pbf row 52 starts at 3744 -> pbf rows 52..63 NEVER dirtied by the overlay
// (init-zero persists); ph3 re-zeroes col-pads 53..63 of rows<=52; ph0
// re-zeroes xinbf pads (addresses disjoint from value scatter -> race-free).
struct __align__(16) BatchState {
  alignas(16) u16   uni[64*XHS];     // pbf / (xin+xinbf) union, 9216 B
  alignas(16) u16   afrag[4*64*8];   // attri as ph4 B-frags (not unioned: live ph1->ph4)
  alignas(16) float srcv[NN*2], dstv[NN*2];
  alignas(16) float inv[56];
  alignas(16) u16   xh[64*XHS];      // MFMA A: [0:32)=gx, [32:64)=h (bf16); pads persist zero
  alignas(16) float h[NN*32];        // fp32 hidden state (carry precision)
};

// ~158.7 KB LDS: 36.2 KB invariant + 4 x 30.4 KB batch state. FOUR batches
// per block -> grid 256 = ONE block per CU = ONE round (r12 needed two).
// Total per-CU work unchanged; the 2nd pair's work fills the ~52% per-step
// stall r12 measured (VALUBusy 48%).
struct __align__(16) Smem {
  alignas(16) float gb[4][96];       // bih_a, bhh_a, bih_m, bhh_m (fp32)
  alignas(16) float embA[304];
  alignas(16) float ctxS[NN][2], ctxD[NN][2];
  alignas(16) float uSrc[2][2][14];
  alignas(16) float uDst[2][2][14];
  alignas(16) u16   biasE[NN*56];    // bf16: adj_norm*a[184] or -1e12
  alignas(16) u16   wfA[2*64*8];     // attri B-frags (nt=0,1): K-rows 0..5=Wxa, 8..11=Wxm, else 0
  alignas(16) u16   wfrag[2*12*64*8]; // GRU B-frags, fragment-ordered (r2-verified)
  BatchState bs[4];
};

// 512 threads, plain bounds -> 128-arch cap; r12's MFMA-ized body measured
// 88 VGPR, and per-batch thread-count halving doubles loop trip counts but
// not live state -> still fits spill-free (go/no-go: FETCH/WRITE stay in MB).
__global__ __launch_bounds__(512)
void chgat_gru_kernel(Params p){
  __shared__ Smem sm;
  const int tid = threadIdx.x;
  const int bid = blockIdx.x;

  // ---------- stage 0: dtype detection (adj is exactly {0,1}) ----------
  bool isbf = false;
  {
    const unsigned* aw = (const unsigned*)p.adj;
    for (int i=0;i<32;++i){
      unsigned w = aw[i];
      if (w != 0u && w != 0x3F800000u) isbf = true;
    }
  }
  // a-vector selector (branchy select, no private array -> no scratch)
  auto aPtr = [&](int s)->const void*{
    return s==0 ? p.a0 : s==1 ? p.a1 : s==2 ? p.a2 : p.a3;
  };

  // ---------- stage 1: stage constants into LDS (batch-invariant) ----------
  if (tid < 96){
    sm.gb[0][tid]=ldf(p.bih_a,tid,isbf); sm.gb[1][tid]=ldf(p.bhh_a,tid,isbf);
    sm.gb[2][tid]=ldf(p.bih_m,tid,isbf); sm.gb[3][tid]=ldf(p.bhh_m,tid,isbf);
  }
  if (tid < 70)  sm.embA[tid]        = ldf(p.emb0, tid, isbf);
  if (tid < 26)  sm.embA[70+tid]     = ldf(p.emb1, tid, isbf);
  if (tid < 14)  sm.embA[96+tid]     = ldf(p.emb2, tid, isbf);
  if (tid < 48)  sm.embA[110+tid]    = ldf(p.emb3, tid, isbf);
  if (tid < 18)  sm.embA[158+tid]    = ldf(p.emb4, tid, isbf);
  if (tid < 36)  sm.embA[176+tid]    = ldf(p.emb5, tid, isbf);
  if (tid < 26)  sm.embA[212+tid]    = ldf(p.emb6, tid, isbf);
  if (tid < 14)  sm.embA[238+tid]    = ldf(p.emb7, tid, isbf);
  if (tid < 48)  sm.embA[252+tid]    = ldf(p.emb8, tid, isbf);
  for (int idx=tid; idx<4*64*XHS; idx+=512) sm.bs[idx/(64*XHS)].uni[idx%(64*XHS)] = 0;
  for (int idx=tid; idx<4*64*XHS; idx+=512) sm.bs[idx/(64*XHS)].xh[idx%(64*XHS)] = 0;
  for (int idx=tid; idx<4*4*64*8; idx+=512) sm.bs[idx/(4*64*8)].afrag[idx%(4*64*8)] = 0;
  for (int idx=tid; idx<4*NN*32; idx+=512) sm.bs[idx/(NN*32)].h[idx%(NN*32)] = 0.f;
  // attri B-frags: one 16x16x32 B per nt; K-rows 0..5 = Wxa, 8..11 = Wxm, else 0
  if (tid < 128){
    int l = tid & 63, nl2 = l & 15, qd2 = l >> 4, nt = tid >> 6;
    u16* dst = &sm.wfA[tid*8];
    #pragma unroll
    for (int j=0;j<8;++j){
      int k = qd2*8 + j, n = nt*16 + nl2;
      u16 v = 0;
      if (k < 6)              v = ldraw(p.Wxa, k*32+n, isbf);
      else if (k>=8 && k<12)  v = ldraw(p.Wxm, (k-8)*32+n, isbf);
      dst[j] = v;
    }
  }
  // GRU weights -> LDS, fragment-ordered (once; 3 lane-frags per thread)
  for (int u = tid; u < 2*12*64; u += 512){
    int wty2 = u / (12*64);
    int rem  = u - wty2*(12*64);
    int f = rem >> 6, l = rem & 63;
    int nl2 = l & 15, qd2 = l >> 4;
    const void* W = (f < 6) ? (wty2 ? p.wih_m : p.wih_a) : (wty2 ? p.whh_m : p.whh_a);
    int fr = (f < 6) ? f : f - 6;
    int base = (fr*16 + nl2)*32 + qd2*8;
    u16* dst = &sm.wfrag[u*8];
    #pragma unroll
    for (int j=0;j<8;++j) dst[j] = ldraw(W, base+j, isbf);
  }
  __syncthreads();

  // ---------- stage 2: batch-invariant attention constants (a-vecs from global) ----------
  if (tid < 212){
    int i = tid>>2, v = tid&3, it = (i<NA)?0:1;
    int sel = (v<2) ? (it*2+v) : ((v-2)*2+it);
    int off = (v<2) ? 32 : 124;
    const void* ap = aPtr(sel);
    float s = 0.f;
    for (int c=0;c<60;++c) s += ldf(p.ctx, i*60+c, isbf)*ldf(ap, off+c, isbf);
    if (v < 2) sm.ctxS[i][v] = s; else sm.ctxD[i][v-2] = s;
  }
  if (tid < 112){
    int u = tid;
    int it = u / 56, rem = u % 56;
    int sd = rem / 28, rem2 = rem % 28;
    int v = rem2 / 14, k = rem2 % 14;
    const void* Wu = it ? p.Wum : p.Wua;
    int sel = sd ? (v*2+it) : (it*2+v);
    int off = sd ? 92 : 0;
    const void* ap = aPtr(sel);
    float s = 0.f;
    for (int kk=0;kk<32;++kk) s += ldf(Wu, k*32+kk, isbf)*ldf(ap, off+kk, isbf);
    if (sd) sm.uDst[it][v][k] = s; else sm.uSrc[it][v][k] = s;
  }
  for (int idx=tid; idx<NN*NN; idx+=512){
    int i = idx/NN, j = idx - i*NN;
    int sel = ((i<NA)?0:2) + ((j<NA)?0:1);
    float ad = ldf(p.adj, idx, isbf);
    sm.biasE[i*56+j] = cvtbf((ad > 0.f) ? ldf(p.adjn, idx, isbf)*ldf(aPtr(sel),184,isbf) : -1e12f);
  }
  __syncthreads();

  // ---------- quarter-block decomposition: 4 batches x 128 threads ----------
  const int hb   = tid >> 7;        // 0..3 (batch within block)
  const int lt   = tid & 127;       // local tid within quarter
  const int lw   = lt >> 6;         // local wave 0..1
  const int lane = tid & 63;        // hardware lane (waves never straddle quarters)
  const int nl   = lane & 15;       // MFMA col/row-in-tile index
  const int qd   = lane >> 4;       // MFMA quad
  const int bb   = 4*bid + hb;      // this quarter's batch element

  BatchState& st = sm.bs[hb];
  u16*   pbf   = st.uni;
  float* xin   = reinterpret_cast<float*>(st.uni);   // bytes [0,3392)
  u16*   xinbf = st.uni + 1696;                      // bytes [3392,7488)

  // slot loaders/scatterers (r3-verified 512-slot map), 4 slots per thread
  auto pref = [&](int slot, int bt)->unsigned{
    if (slot < 210) return __float_as_uint(ldf(p.X_aqi, bt*210 + slot, isbf));
    if (slot < 282) return __float_as_uint(ldf(p.X_meo, bt*72 + slot - 210, isbf));
    if (slot < 422) return (unsigned)p.Xae[bt*140 + slot - 282];
    return (unsigned)p.Xme[bt*90 + slot - 422];
  };
  auto scat = [&](int slot, unsigned bits){
    if (slot < 210){
      int n = slot/6, e = slot%6;
      float v = __uint_as_float(bits);
      xin[n*16 + e] = v;
      xinbf[n*32 + e] = cvtbf(v);                 // aqi K-rows 0..5
    } else if (slot < 282){
      int q = slot-210; int n = NA + (q>>2), e = q&3;
      float v = __uint_as_float(bits);
      xin[n*16 + e] = v;
      xinbf[n*32 + 8 + e] = cvtbf(v);             // meo K-rows 8..11
    } else if (slot < 422){
      int u = slot - 282;
      int n = u>>2, e = u&3;
      int off = (e==0)?0:(e==1)?70:(e==2)?96:110;
      xin[n*16 + 6 + 2*e]     = sm.embA[off + (int)bits*2];
      xin[n*16 + 6 + 2*e + 1] = sm.embA[off + (int)bits*2 + 1];
    } else {
      int q = slot - 422;
      int n = NA + q/5, e = q%5;
      int off = (e==0)?158:(e==1)?176:(e==2)?212:(e==3)?238:252;
      xin[n*16 + 4 + 2*e]     = sm.embA[off + (int)bits*2];
      xin[n*16 + 4 + 2*e + 1] = sm.embA[off + (int)bits*2 + 1];
    }
  };

  // ---------- prefetch t=0 ----------
  unsigned rv0, rv1, rv2, rv3;
  {
    int bt = bb*TT + 0;
    rv0 = pref(lt      , bt);
    rv1 = pref(lt + 128, bt);
    rv2 = pref(lt + 256, bt);
    rv3 = pref(lt + 384, bt);
  }

  #pragma unroll 1
  for (int t=0; t<TT; ++t){
    // ---- ph0: scatter inputs (values) + re-zero xinbf pads (disjoint addrs) ----
    scat(lt      , rv0);
    scat(lt + 128, rv1);
    scat(lt + 256, rv2);
    scat(lt + 384, rv3);
    {
      int row = lt >> 1, c0 = (lt & 1) * 16;
      #pragma unroll
      for (int c = 0; c < 16; ++c){
        int col = c0 + c;
        bool isval = (row < NA) ? (col < 6) : (row < NN ? (col >= 8 && col < 12) : false);
        if (!isval) xinbf[row*32 + col] = 0;
      }
    }
    // prefetch t+1
    {
      int tn = (t < TT-1) ? t+1 : t;
      int bt = bb*TT + tn;
      rv0 = pref(lt      , bt);
      rv1 = pref(lt + 128, bt);
      rv2 = pref(lt + 256, bt);
      rv3 = pref(lt + 384, bt);
    }
    __syncthreads();   // (A) xin/xinbf ready; prior-step h writes visible

    // ---- ph1: attri via MFMA (wave lw -> M-tiles 2lw,2lw+1; both nt) + logits ----
    {
      #pragma unroll 1
      for (int mi=0; mi<2; ++mi){
        int mt = lw*2 + mi;
        s8v A0 = *(const s8v*)&xinbf[(mt*16 + nl)*32 + qd*8];
        #pragma unroll 1
        for (int nt=0; nt<2; ++nt){
          s8v B0 = ((const s8v*)sm.wfA)[nt*64 + lane];
          f4v acc = {0,0,0,0};
          acc = __builtin_amdgcn_mfma_f32_16x16x32_bf16(A0, B0, acc, 0,0,0);
          #pragma unroll
          for (int r=0;r<4;++r){
            int row = mt*16 + qd*4 + r;   // node; C/D: col=lane&15, row=(lane>>4)*4+reg
            if (row < NN){
              int fi = ((row>>5)*2 + nt)*64 + (nl + (((row>>3)&3)<<4));
              st.afrag[fi*8 + (row&7)] = cvtbf(acc[r]);
            }
          }
        }
      }
    }
    for (int it = lt; it < 212; it += 128){
      int i = it>>2, v = it&3, it2 = (i<NA)?0:1;
      const float* x = &xin[i*16];
      float sacc; const float* uv;
      if (v < 2){ sacc = sm.ctxS[i][v];   uv = sm.uSrc[it2][v]; }
      else      { sacc = sm.ctxD[i][v-2]; uv = sm.uDst[it2][v-2]; }
      #pragma unroll
      for (int k=0;k<14;++k) sacc += x[k]*uv[k];
      if (v < 2) st.srcv[i*2+v] = sacc; else st.dstv[i*2+(v-2)] = sacc;
    }
    __syncthreads();   // (B) afrag, srcv, dstv ready; xin/xinbf now dead

    // ---- ph3: masked softmax (2 lanes/row); writes P bf16 + zero col-pads ----
    if (lt < 106){
      int i = lt>>1, l = lt&1, it2 = (i<NA)?0:1;
      float s0 = st.srcv[i*2+0], s1 = st.srcv[i*2+1];
      float mx = -3.0e38f;
      for (int j=l; j<NN; j+=2){
        float e = ((j<NA)? s0 : s1) + st.dstv[j*2+it2] + bfu(sm.biasE[i*56+j]);
        e = (e >= 0.f) ? e : 0.2f*e;
        mx = fmaxf(mx, e);
      }
      mx = fmaxf(mx, __shfl_xor(mx,1,64));
      float sum = 0.f;
      for (int j=l; j<NN; j+=2){
        float e = ((j<NA)? s0 : s1) + st.dstv[j*2+it2] + bfu(sm.biasE[i*56+j]);
        e = (e >= 0.f) ? e : 0.2f*e;
        float pe = __expf(e - mx);
        pbf[i*XHS+j] = cvtbf(pe);     // unnormalized P, bf16 (A operand)
        sum += pe;
      }
      sum += __shfl_xor(sum,1,64);
      if (l == 0) st.inv[i] = 1.0f/sum;
      for (int j2 = 53+l; j2 < 64; j2 += 2) pbf[i*XHS+j2] = 0;  // re-zero col pads dirtied by overlay
    }
    __syncthreads();   // (C) pbf, inv ready (rows 52..63 pristine zero from init)

    // ---- ph4: gx = (P @ attri) * inv via MFMA; wave lw -> M-tiles 2lw,2lw+1 ----
    {
      #pragma unroll 1
      for (int mi=0; mi<2; ++mi){
        int mt = lw*2 + mi;
        const u16* arow = &pbf[(mt*16 + nl)*XHS + qd*8];
        s8v A0 = *(const s8v*)arow;            // k 0..31
        s8v A1 = *(const s8v*)(arow + 32);     // k 32..63 (cols 53-63 zero)
        const s8v* bf = (const s8v*)st.afrag;
        #pragma unroll 1
        for (int nt=0; nt<2; ++nt){
          s8v B0 = bf[(0*2+nt)*64 + lane];
          s8v B1 = bf[(1*2+nt)*64 + lane];
          f4v acc = {0,0,0,0};
          acc = __builtin_amdgcn_mfma_f32_16x16x32_bf16(A0, B0, acc, 0,0,0);
          acc = __builtin_amdgcn_mfma_f32_16x16x32_bf16(A1, B1, acc, 0,0,0);
          const int dcol = nt*16 + nl;
          #pragma unroll
          for (int r=0;r<4;++r){
            int row = mt*16 + qd*4 + r;    // C/D: col=lane&15, row=(lane>>4)*4+reg
            if (row < NN) st.xh[row*XHS + dcol] = cvtbf(acc[r] * st.inv[row]);
          }
        }
      }
    }
    __syncthreads();   // (D) xh x-part ready; pbf dead (safe for next ph0 overlay)

    // ---- ph5: GRU via MFMA; lw0: (0,a),(1,a); lw1: (2,a),(2,m),(3,m).
    // hf half-pass split keeps live pressure to {A0,A1, 4 accums, 6 frags}.
    {
      const bool last = (t == TT-1);
      auto run_pass = [&](int mt, int tp){
        const s8v* wfB = ((const s8v*)sm.wfrag) + (tp*12*64 + lane);
        const u16* xr = &st.xh[(mt*16 + nl)*XHS + qd*8];
        s8v A0 = *(const s8v*)xr;          // k 0..31 (x)
        s8v A1 = *(const s8v*)(xr + 32);   // k 32..63 (h)
        const float* bi = tp ? sm.gb[2] : sm.gb[0];
        const float* bh = tp ? sm.gb[3] : sm.gb[1];
        #pragma unroll 1
        for (int hf=0; hf<2; ++hf){
          f4v aR={0,0,0,0}, aZ={0,0,0,0}, aI={0,0,0,0}, aG={0,0,0,0};
          aR = __builtin_amdgcn_mfma_f32_16x16x32_bf16(A0, wfB[(0+hf)*64],  aR, 0,0,0);
          aR = __builtin_amdgcn_mfma_f32_16x16x32_bf16(A1, wfB[(6+hf)*64],  aR, 0,0,0);
          aZ = __builtin_amdgcn_mfma_f32_16x16x32_bf16(A0, wfB[(2+hf)*64],  aZ, 0,0,0);
          aZ = __builtin_amdgcn_mfma_f32_16x16x32_bf16(A1, wfB[(8+hf)*64],  aZ, 0,0,0);
          aI = __builtin_amdgcn_mfma_f32_16x16x32_bf16(A0, wfB[(4+hf)*64],  aI, 0,0,0);
          aG = __builtin_amdgcn_mfma_f32_16x16x32_bf16(A1, wfB[(10+hf)*64], aG, 0,0,0);
          const int dd = nl + hf*16;
          float br=bi[dd]+bh[dd], bz=bi[32+dd]+bh[32+dd], bn=bi[64+dd], bg=bh[64+dd];
          #pragma unroll
          for (int r=0;r<4;++r){
            int node = mt*16 + qd*4 + r;      // C/D layout: row=(lane>>4)*4+reg
            bool valid = tp ? (node>=NA && node<NN) : (node<NA);
            if (valid){
              float hold = st.h[node*32+dd];
              float rr = 1.f/(1.f+__expf(-(aR[r]+br)));
              float zz = 1.f/(1.f+__expf(-(aZ[r]+bz)));
              float pr = (aI[r]+bn) + rr*(aG[r]+bg);
              float e2 = __expf(2.f*pr);
              float hn = (1.f-zz)*(1.f-2.f/(e2+1.f)) + zz*hold;
              st.h[node*32+dd] = hn;
              st.xh[node*XHS+32+dd] = cvtbf(hn);
              if (last){
                long long oi = tp ? ((long long)OUT_MEO_BASE + (long long)bb*(NM*HH) + (long long)(node-NA)*32)
                                  : ((long long)bb*(NA*HH) + (long long)node*32);
                if (isbf) ((u16*)p.out)[oi+dd]=cvtbf(hn);
                else      ((float*)p.out)[oi+dd]=hn;
              }
            }
          }
        }
      };
      if (lw == 0){ run_pass(0,0); run_pass(1,0); }
      else        { run_pass(2,0); run_pass(2,1); run_pass(3,1); }
    }
    // loop tail: epilogue h writes ordered vs next step's readers by barrier (A)
  }
}

extern "C" void kernel_launch(void* const* d_in, const int* in_sizes, int n_in,
                              void* d_out, int out_size, void* d_ws, size_t ws_size,
                              hipStream_t stream){
  (void)in_sizes; (void)n_in; (void)d_ws; (void)ws_size; (void)out_size;
  Params p;
  p.X_aqi = d_in[0];
  p.X_meo = d_in[1];
  p.ctx   = d_in[2];
  p.adj   = d_in[3];
  p.adjn  = d_in[4];
  p.emb0 = d_in[5];  p.emb1 = d_in[6];
  p.emb2 = d_in[7];  p.emb3 = d_in[8];
  p.emb4 = d_in[9];  p.emb5 = d_in[10];
  p.emb6 = d_in[11]; p.emb7 = d_in[12];
  p.emb8 = d_in[13];
  p.Wxa = d_in[14]; p.Wxm = d_in[15];
  p.Wua = d_in[16]; p.Wum = d_in[17];
  p.a0 = d_in[18]; p.a1 = d_in[19];
  p.a2 = d_in[20]; p.a3 = d_in[21];
  p.wih_a = d_in[22]; p.whh_a = d_in[23];
  p.bih_a = d_in[24]; p.bhh_a = d_in[25];
  p.wih_m = d_in[26]; p.whh_m = d_in[27];
  p.bih_m = d_in[28]; p.bhh_m = d_in[29];
  p.Xae = (const int*)d_in[30];
  p.Xme = (const int*)d_in[31];
  p.out = d_out;
  hipLaunchKernelGGL(chgat_gru_kernel, dim3(256), dim3(512), 0, stream, p);
}